// Round 5
// baseline (191.337 us; speedup 1.0000x reference)
//
#include <hip/hip_runtime.h>

// Match numpy f32 semantics: no FMA contraction anywhere in this TU.
#pragma clang fp contract(off)

#define VWD 96
#define NVERT 2048
#define NFAC 512
#define NBATCH 8
#define NSLAB 3456          // 12 x 12 x 24 slabs of 8x8x4 voxels
#define RECF 16             // floats per facet body record
#define CULC 26             // cull components (SoA): bbox 6 + 4 planes x 4 + 4 containment deltas
#define HEAVY_T 32          // candidate-count threshold: <=T serial wave, >T 8-wave block

// SoA cull addressing: component c, batch b, facet f
#define CUL(c, b, f) cul[(size_t)(c) * (NBATCH * NFAC) + (size_t)(b) * NFAC + (f)]

// ---------------------------------------------------------------------------
// Kernel 1: per-batch facet precompute, ordered by |det| descending via a
// ONE-BARRIER rank sort. Fully scalarized. Body records SIGN-FOLDED: det<0 =>
// negate A,det (IEEE negation commutes exactly through mul/add/div, so
// n'/det' == n/det bit-for-bit).
//   body[b][s][16] : det,v3x,v3y,v3z, A00..A22, dhi, mhi, pad
//   dhi = det*(1-1e-5) - 1e-25   (definite-inside upper bound on sum)
//   mhi = det*(1+1e-5) + 1e-25   (maybe-inside upper bound; +-1e-25 guards
//                                 det=0 degenerate facets: ref l=NaN=outside)
// Per-plane containment delta D_i = -(M + 2E + 2e-3): slab center passing
// d_i <= D_i for all 4 planes => whole slab definitely inside (convexity,
// margin >= 2e-3 - eval_err ~ 1.8e-3 >> ref rounding shell; normal row and
// adjugate row are both 2*face-area so |det| cancels in barycentric units;
// degenerate facets have max interior distance ~0 and cannot pass).
// ---------------------------------------------------------------------------
__global__ __launch_bounds__(512) void precompute_kernel(
    const float* __restrict__ vertices,
    const int*   __restrict__ facets,
    float*       __restrict__ cul,
    float*       __restrict__ body)
{
    __shared__ unsigned skey[NFAC];
    const int b = blockIdx.x;
    const int j = threadIdx.x;          // one facet per thread
    const float* vb = vertices + (size_t)b * NVERT * 3;

    int4 fi = ((const int4*)facets)[b * NFAC + j];
    float x0 = vb[3*fi.x+0], y0 = vb[3*fi.x+1], z0 = vb[3*fi.x+2];
    float x1 = vb[3*fi.y+0], y1 = vb[3*fi.y+1], z1 = vb[3*fi.y+2];
    float x2 = vb[3*fi.z+0], y2 = vb[3*fi.z+1], z2 = vb[3*fi.z+2];
    float x3 = vb[3*fi.w+0], y3 = vb[3*fi.w+1], z3 = vb[3*fi.w+2];
    float a  = x0-x3, bb = x1-x3, c  = x2-x3;
    float d  = y0-y3, e  = y1-y3, f  = y2-y3;
    float g  = z0-z3, h  = z1-z3, ii = z2-z3;
    float A00 = e*ii - f*h,  A01 = c*h  - bb*ii, A02 = bb*f - c*e;
    float A10 = f*g  - d*ii, A11 = a*ii - c*g,   A12 = c*d  - a*f;
    float A20 = d*h  - e*g,  A21 = bb*g - a*h,   A22 = a*e  - bb*d;
    float det = a*(e*ii - f*h) - bb*(d*ii - f*g) + c*(d*h - e*g);
    if (det < 0.0f) {   // sign-fold (exact)
        det = -det;
        A00 = -A00; A01 = -A01; A02 = -A02;
        A10 = -A10; A11 = -A11; A12 = -A12;
        A20 = -A20; A21 = -A21; A22 = -A22;
    }
    unsigned myk = ~__float_as_uint(det);   // ascending key == descending |det|
    skey[j] = myk;
    __syncthreads();

    // rank = #{k : key_k < myk or (key_k == myk and k < j)}  -> unique slot
    int rank = 0;
    const uint4* sk4 = (const uint4*)skey;
    for (int k0 = 0; k0 < NFAC; k0 += 4) {
        uint4 kk = sk4[k0 >> 2];
        rank += (kk.x < myk) + ((kk.x == myk) & (k0 + 0 < j));
        rank += (kk.y < myk) + ((kk.y == myk) & (k0 + 1 < j));
        rank += (kk.z < myk) + ((kk.z == myk) & (k0 + 2 < j));
        rank += (kk.w < myk) + ((kk.w == myk) & (k0 + 3 < j));
    }

    CUL(0, b, rank) = fminf(fminf(x0,x1),fminf(x2,x3)) - 1e-4f;
    CUL(1, b, rank) = fminf(fminf(y0,y1),fminf(y2,y3)) - 1e-4f;
    CUL(2, b, rank) = fminf(fminf(z0,z1),fminf(z2,z3)) - 1e-4f;
    CUL(3, b, rank) = fmaxf(fmaxf(x0,x1),fmaxf(x2,x3)) + 1e-4f;
    CUL(4, b, rank) = fmaxf(fmaxf(y0,y1),fmaxf(y2,y3)) + 1e-4f;
    CUL(5, b, rank) = fmaxf(fmaxf(z0,z1),fmaxf(z2,z3)) + 1e-4f;

    // 4 outward face planes, margin-inflated, slab half-extents folded:
    // overlap test becomes  dot(n, slab_center) - rhs <= 0   (conservative).
    // containment test:     dot(n, slab_center) - rhs <= D   (definite).
    const float HX = 7.0f/96.0f, HZ = 3.0f/96.0f;
    auto plane = [&](float pax, float pay, float paz,
                     float pbx, float pby, float pbz,
                     float pcx, float pcy, float pcz,
                     float pox, float poy, float poz, int base, int pi) {
        float e1x = pbx-pax, e1y = pby-pay, e1z = pbz-paz;
        float e2x = pcx-pax, e2y = pcy-pay, e2z = pcz-paz;
        float nx = e1y*e2z - e1z*e2y;
        float ny = e1z*e2x - e1x*e2z;
        float nz = e1x*e2y - e1y*e2x;
        float sdot = nx*(pox-pax) + ny*(poy-pay) + nz*(poz-paz);
        if (sdot > 0.0f) { nx=-nx; ny=-ny; nz=-nz; sdot=-sdot; }
        float dpl = nx*pax + ny*pay + nz*paz;
        float n1s = fabsf(nx)+fabsf(ny)+fabsf(nz);
        float M = 1e-4f*(-sdot) + 1e-4f*n1s + 1e-4f;
        float E = fabsf(nx)*HX + fabsf(ny)*HX + fabsf(nz)*HZ;
        float rhs = dpl + M + E;
        CUL(base+0, b, rank) = nx;
        CUL(base+1, b, rank) = ny;
        CUL(base+2, b, rank) = nz;
        CUL(base+3, b, rank) = rhs;
        CUL(22+pi, b, rank) = -(M + 2.0f*E + 2e-3f);   // containment delta
    };
    plane(x1,y1,z1, x2,y2,z2, x3,y3,z3, x0,y0,z0, 6, 0);    // opposite v0
    plane(x0,y0,z0, x2,y2,z2, x3,y3,z3, x1,y1,z1, 10, 1);   // opposite v1
    plane(x0,y0,z0, x1,y1,z1, x3,y3,z3, x2,y2,z2, 14, 2);   // opposite v2
    plane(x0,y0,z0, x1,y1,z1, x2,y2,z2, x3,y3,z3, 18, 3);   // opposite v3

    float* bo = body + ((size_t)b * NFAC + rank) * RECF;
    bo[0]  = det; bo[1]  = x3;  bo[2]  = y3;  bo[3]  = z3;
    bo[4]  = A00; bo[5]  = A01; bo[6]  = A02; bo[7]  = A10;
    bo[8]  = A11; bo[9]  = A12; bo[10] = A20; bo[11] = A21;
    bo[12] = A22;
    bo[13] = det * (1.0f - 1e-5f) - 1e-25f;   // dhi
    bo[14] = det * (1.0f + 1e-5f) + 1e-25f;   // mhi
    bo[15] = 0.0f;
}

// ---------------------------------------------------------------------------
// Kernel 2: per-slab 512-bit facet mask + per-slab "fully contained" flag.
// One block per (batch, x-y column); facet-per-lane, cull record loaded ONCE
// (SoA, coalesced), 24 z-slabs via incremental plane dots (error ~1e-4 <<
// margins folded into rhs / delta).
// ---------------------------------------------------------------------------
__global__ __launch_bounds__(512) void mask_kernel(
    const float* __restrict__ cul,
    unsigned long long* __restrict__ masks,
    unsigned* __restrict__ fullmask)
{
    __shared__ unsigned fullbits;
    const int col = blockIdx.x;           // 0..143 = sx*12+sy
    const int b   = blockIdx.y;
    const int f   = threadIdx.x;          // facet (sorted order)
    const int w   = threadIdx.x >> 6;
    if (threadIdx.x == 0) fullbits = 0u;
    __syncthreads();
    float bminx=CUL(0,b,f), bminy=CUL(1,b,f), bminz=CUL(2,b,f);
    float bmaxx=CUL(3,b,f), bmaxy=CUL(4,b,f), bmaxz=CUL(5,b,f);
    float n0x=CUL(6,b,f),  n0y=CUL(7,b,f),  n0z=CUL(8,b,f),  r0=CUL(9,b,f);
    float n1x=CUL(10,b,f), n1y=CUL(11,b,f), n1z=CUL(12,b,f), r1=CUL(13,b,f);
    float n2x=CUL(14,b,f), n2y=CUL(15,b,f), n2z=CUL(16,b,f), r2=CUL(17,b,f);
    float n3x=CUL(18,b,f), n3y=CUL(19,b,f), n3z=CUL(20,b,f), r3=CUL(21,b,f);
    float D0=CUL(22,b,f), D1=CUL(23,b,f), D2=CUL(24,b,f), D3=CUL(25,b,f);

    const int sx = col / 12, sy = col % 12;
    const float cx = (float)(16*sx + 8 - VWD) / 96.0f;
    const float cy = (float)(16*sy + 8 - VWD) / 96.0f;
    const float colminx = (float)(16*sx + 1  - VWD) / 96.0f;
    const float colmaxx = (float)(16*sx + 15 - VWD) / 96.0f;
    const float colminy = (float)(16*sy + 1  - VWD) / 96.0f;
    const float colmaxy = (float)(16*sy + 15 - VWD) / 96.0f;
    const bool ovxy = (bminx <= colmaxx) & (bmaxx >= colminx) &
                      (bminy <= colmaxy) & (bmaxy >= colminy);

    const float cz0   = (float)(4 - VWD) / 96.0f;   // z-center of slab sz=0
    const float stepc = 8.0f / 96.0f;
    float d0 = n0x*cx + n0y*cy + n0z*cz0 - r0;  float s0 = n0z*stepc;
    float d1 = n1x*cx + n1y*cy + n1z*cz0 - r1;  float s1 = n1z*stepc;
    float d2 = n2x*cx + n2y*cy + n2z*cz0 - r2;  float s2 = n2z*stepc;
    float d3 = n3x*cx + n3y*cy + n3z*cz0 - r3;  float s3 = n3z*stepc;
    float zlo = (float)(1 - VWD) / 96.0f;
    float zhi = (float)(7 - VWD) / 96.0f;

    unsigned fullw = 0u;
    unsigned long long* mp = masks + ((size_t)b * NSLAB + (size_t)col * 24) * 8 + w;
#pragma unroll 4
    for (int sz = 0; sz < 24; ++sz) {
        bool ov = ovxy & (bminz <= zhi) & (bmaxz >= zlo) &
                  (d0 <= 0.0f) & (d1 <= 0.0f) & (d2 <= 0.0f) & (d3 <= 0.0f);
        bool fullv = (d0 <= D0) & (d1 <= D1) & (d2 <= D2) & (d3 <= D3);
        unsigned long long bal = __ballot((int)ov);
        if ((threadIdx.x & 63) == 0) mp[(size_t)sz * 8] = bal;
        if (__ballot((int)fullv) != 0ull) fullw |= (1u << sz);
        d0 += s0; d1 += s1; d2 += s2; d3 += s3;
        zlo += stepc; zhi += stepc;
    }
    if ((threadIdx.x & 63) == 0 && fullw) atomicOr(&fullbits, fullw);
    __syncthreads();
    if (threadIdx.x == 0) fullmask[b * 144 + col] = fullbits;
}

// Facet body record in wave-uniform (SGPR) registers.
struct Rec {
    float det, v3x, v3y, v3z;
    float A00, A01, A02, A10, A11, A12, A20, A21, A22;
    float dhi, mhi;
};

__device__ __forceinline__ void load_rec(Rec& r, const float* __restrict__ bo)
{
    float4 q0 = *(const float4*)(bo + 0);
    float4 q1 = *(const float4*)(bo + 4);
    float4 q2 = *(const float4*)(bo + 8);
    float4 q3 = *(const float4*)(bo + 12);
    r.det = q0.x; r.v3x = q0.y; r.v3y = q0.z; r.v3z = q0.w;
    r.A00 = q1.x; r.A01 = q1.y; r.A02 = q1.z; r.A10 = q1.w;
    r.A11 = q2.x; r.A12 = q2.y; r.A20 = q2.z; r.A21 = q2.w;
    r.A22 = q3.x; r.dhi = q3.y; r.mhi = q3.z;
}

// ---------------------------------------------------------------------------
// Per-candidate exact test on a register-resident record. Numerators
// bit-identical to ref; exact l_i>=0 sign test; det-relative shell on the
// sum; per-lane 4-bit `need` mask so only ONE __any branch per candidate
// guards the (rare) exact-division path.
// ---------------------------------------------------------------------------
__device__ __forceinline__ void facet_test_reg(
    const Rec& rr,
    float px, float py, float pz0, float pz1, float pz2, float pz3,
    unsigned& fnd)
{
    float dx = px - rr.v3x, dy = py - rr.v3y;
    // ref-exact partials (left-assoc, contract off)
    float p0 = rr.A00*dx + rr.A01*dy;
    float p1 = rr.A10*dx + rr.A11*dy;
    float p2 = rr.A20*dx + rr.A21*dy;
    float dzk0 = pz0 - rr.v3z, dzk1 = pz1 - rr.v3z;
    float dzk2 = pz2 - rr.v3z, dzk3 = pz3 - rr.v3z;
    unsigned need = 0u;   // bit k: lane in shell, must run exact path
#pragma unroll
    for (int k = 0; k < 4; ++k) {
        float dzk = (k == 0) ? dzk0 : (k == 1) ? dzk1
                  : (k == 2) ? dzk2 : dzk3;
        // n_i bit-identical to reference's numerators
        float n0 = p0 + rr.A02*dzk;
        float n1 = p1 + rr.A12*dzk;
        float n2 = p2 + rr.A22*dzk;
        float sm = (n0 + n1) + n2;
        float mn = fminf(fminf(n0, n1), n2);   // v_min3_f32
        bool ge0 = (mn >= 0.0f);               // EXACT l_i>=0 test
        bool def = ge0 & (sm <= rr.dhi);
        bool may = ge0 & (sm <= rr.mhi);
        if (may & !def & !((fnd >> k) & 1u)) need |= (1u << k);
        if (def) fnd |= (1u << k);
    }
    if (__any(need != 0u)) {
        // exact path (rare): ref's divisions + final test, per k
#pragma unroll
        for (int k = 0; k < 4; ++k) {
            float dzk = (k == 0) ? dzk0 : (k == 1) ? dzk1
                      : (k == 2) ? dzk2 : dzk3;
            float n0 = p0 + rr.A02*dzk;
            float n1 = p1 + rr.A12*dzk;
            float n2 = p2 + rr.A22*dzk;
            float l0 = n0 / rr.det;
            float l1 = n1 / rr.det;
            float l2 = n2 / rr.det;
            float l3 = 1.0f - ((l0 + l1) + l2);
            bool inside = (l0 >= 0.0f) & (l0 <= 1.0f) &
                          (l1 >= 0.0f) & (l1 <= 1.0f) &
                          (l2 >= 0.0f) & (l2 <= 1.0f) &
                          (l3 >= 0.0f) & (l3 <= 1.0f);
            if (((need >> k) & 1u) & inside) fnd |= (1u << k);
        }
    }
}

// ---------------------------------------------------------------------------
// Kernel 3a (LIGHT, total<=HEAVY_T): R0-style wave-per-slab, 2-wave blocks,
// ZERO LDS / ZERO barriers (R4 lesson: list build + barriers = 27% of the
// kernel, paid even by 2-test slabs). Serial scan in sorted order with
// 2-deep uniform record prefetch (fixes R0's exposed s_load chain, 50%
// VALUBusy). Heavy slabs return untouched (disjoint ownership by the
// uniform popcount predicate). XCD sector swizzle kept.
// ---------------------------------------------------------------------------
__global__ __launch_bounds__(128) void voxelize_light(
    const float*              __restrict__ body,
    const unsigned long long* __restrict__ masks,
    const unsigned*           __restrict__ fullmask,
    float*                    __restrict__ out)
{
    const int b    = blockIdx.y;
    const int wave = threadIdx.x >> 6;
    const int lane = threadIdx.x & 63;
    const int B    = blockIdx.x;                    // 0..1727
    const int pr   = B & 15;
    const int pair = (B >> 4) * 16 + (pr & 7) * 2 + (pr >> 3);
    const int slab = pair * 2 + wave;               // 0 .. 3455
    const int sz  = slab % 24;
    const int col = slab / 24;
    const int sy  = col % 12;
    const int sx  = slab / 288;
    const int ix  = sx*8 + (lane >> 3);
    const int iy  = sy*8 + (lane & 7);
    const int iz0 = sz*4;
    float* op = &out[(size_t)b*(VWD*VWD*VWD) + (size_t)ix*(VWD*VWD) + iy*VWD + iz0];

    unsigned fnd = 0u;

    // fully-contained slab: convexity => every voxel definitely inside.
    if ((fullmask[b * 144 + col] >> sz) & 1u) { fnd = 15u; goto lwrite; }

    {
        const unsigned long long* mp = masks + ((size_t)b * NSLAB + slab) * 8;
        const unsigned long long w0 = mp[0], w1 = mp[1], w2 = mp[2], w3 = mp[3];
        const unsigned long long w4 = mp[4], w5 = mp[5], w6 = mp[6], w7 = mp[7];
        const int total = __popcll(w0) + __popcll(w1) + __popcll(w2) +
                          __popcll(w3) + __popcll(w4) + __popcll(w5) +
                          __popcll(w6) + __popcll(w7);
        if (total > HEAVY_T) return;        // heavy kernel owns this slab
        if (total == 0) goto lwrite;        // fnd = 0

        const float px  = (float)(2*ix + 1 - VWD) / 96.0f;
        const float py  = (float)(2*iy + 1 - VWD) / 96.0f;
        const float pz0 = (float)(2*(iz0+0) + 1 - VWD) / 96.0f;
        const float pz1 = (float)(2*(iz0+1) + 1 - VWD) / 96.0f;
        const float pz2 = (float)(2*(iz0+2) + 1 - VWD) / 96.0f;
        const float pz3 = (float)(2*(iz0+3) + 1 - VWD) / 96.0f;
        const float* bb = body + (size_t)b * NFAC * RECF;

        // register cursor over the 8 words (no memory in advance)
        unsigned long long cm = w0; int cwi = 0;
        auto adv = [&]() -> int {
            while (cm == 0ull) {
                if (cwi >= 7) return -1;
                ++cwi;
                cm = (cwi==1)?w1:(cwi==2)?w2:(cwi==3)?w3:(cwi==4)?w4:
                     (cwi==5)?w5:(cwi==6)?w6:w7;
            }
            int bit = __builtin_ctzll(cm);
            cm &= cm - 1ull;
            return (cwi << 6) + bit;
        };

        int fa = adv();                    // valid (total > 0)
        int fb = adv();                    // index of 2nd test (may be -1)
        int fc;
        Rec r0, r1, r2;
        load_rec(r0, bb + (size_t)fa * RECF);
        load_rec(r1, bb + (size_t)(fb >= 0 ? fb : fa) * RECF);

        // 3-rotation: no register copies; prefetch depth 2.
#define LSTEP(RC, RP)                                                   \
        {                                                               \
            fc = adv();                                                 \
            load_rec(RP, bb + (size_t)(fc >= 0 ? fc : fa) * RECF);      \
            facet_test_reg(RC, px, py, pz0, pz1, pz2, pz3, fnd);        \
            if (__all(fnd == 15u) || fb < 0) goto lwrite;               \
            fb = fc;                                                    \
        }
        for (;;) { LSTEP(r0, r2) LSTEP(r1, r0) LSTEP(r2, r1) }
#undef LSTEP
    }
lwrite:
    {
        float4 v;
        v.x = (fnd & 1u) ? 1.0f : 0.0f;
        v.y = (fnd & 2u) ? 1.0f : 0.0f;
        v.z = (fnd & 4u) ? 1.0f : 0.0f;
        v.w = (fnd & 8u) ? 1.0f : 0.0f;
        *(float4*)op = v;
    }
}

// ---------------------------------------------------------------------------
// Kernel 3b (HEAVY, total>HEAVY_T): one 8-wave block per slab. Each wave
// popcounts ALL 8 words locally (no cnt[] barrier); quick uniform exits for
// full / light slabs cost one scalar read + 8 loads. List build (wave w
// extracts word w's bits lane-parallel), then strided scan with:
//  - lst value prefetched ONE step ahead (readfirstlane's lgkmcnt wait lands
//    under the previous facet test),
//  - record prefetched TWO steps ahead (s_load ~200-400 cyc covered),
//  - fl[lane] cross-wave union read prefetched one step ahead (stale-by-one
//    is safe: monotonic OR; it only delays early exit by <=1 iteration).
// ---------------------------------------------------------------------------
__global__ __launch_bounds__(512) void voxelize_heavy(
    const float*              __restrict__ body,
    const unsigned long long* __restrict__ masks,
    const unsigned*           __restrict__ fullmask,
    float*                    __restrict__ out)
{
    __shared__ unsigned short lst[NFAC];
    __shared__ unsigned fl[64];

    const int b    = blockIdx.y;
    const int B    = blockIdx.x;                    // 0..3455
    const int r    = B & 31;
    const int slab = (B >> 5) * 32 + (r & 7) * 4 + (r >> 3);
    const int wave = threadIdx.x >> 6;              // 0..7 -> mask word
    const int lane = threadIdx.x & 63;
    const int sz  = slab % 24;
    const int col = slab / 24;
    const int sy  = col % 12;
    const int sx  = slab / 288;
    const int ix  = sx*8 + (lane >> 3);
    const int iy  = sy*8 + (lane & 7);
    const int iz0 = sz*4;

    // light kernel owns full slabs too (uniform predicate -> whole block exits)
    if ((fullmask[b * 144 + col] >> sz) & 1u) return;

    const unsigned long long* mp = masks + ((size_t)b * NSLAB + slab) * 8;
    const unsigned long long w0 = mp[0], w1 = mp[1], w2 = mp[2], w3 = mp[3];
    const unsigned long long w4 = mp[4], w5 = mp[5], w6 = mp[6], w7 = mp[7];
    const int c0 = __popcll(w0), c1 = __popcll(w1), c2 = __popcll(w2),
              c3 = __popcll(w3), c4 = __popcll(w4), c5 = __popcll(w5),
              c6 = __popcll(w6), c7 = __popcll(w7);
    const int total = c0+c1+c2+c3+c4+c5+c6+c7;
    if (total <= HEAVY_T) return;                   // light kernel owns it

    // local prefix for this wave's word; own word + popcount from registers
    const unsigned long long mw = (wave==0)?w0:(wave==1)?w1:(wave==2)?w2:
                                  (wave==3)?w3:(wave==4)?w4:(wave==5)?w5:
                                  (wave==6)?w6:w7;
    const int cw = (wave==0)?c0:(wave==1)?c1:(wave==2)?c2:
                   (wave==3)?c3:(wave==4)?c4:(wave==5)?c5:
                   (wave==6)?c6:c7;
    int off = 0;
    if (wave > 0) off += c0; if (wave > 1) off += c1;
    if (wave > 2) off += c2; if (wave > 3) off += c3;
    if (wave > 4) off += c4; if (wave > 5) off += c5;
    if (wave > 6) off += c6;

    if (threadIdx.x < 64) fl[threadIdx.x] = 0u;
    if (lane < cw) {
        // lane -> position of its (lane+1)-th set bit (binary halving)
        unsigned long long m = mw; int rr = lane, pos = 0; unsigned c;
        c = (unsigned)__popcll(m & 0xFFFFFFFFull);
        if ((unsigned)rr >= c) { rr -= c; m >>= 32; pos += 32; }
        c = (unsigned)__popcll(m & 0xFFFFull);
        if ((unsigned)rr >= c) { rr -= c; m >>= 16; pos += 16; }
        c = (unsigned)__popcll(m & 0xFFull);
        if ((unsigned)rr >= c) { rr -= c; m >>= 8;  pos += 8; }
        c = (unsigned)__popcll(m & 0xFull);
        if ((unsigned)rr >= c) { rr -= c; m >>= 4;  pos += 4; }
        c = (unsigned)__popcll(m & 0x3ull);
        if ((unsigned)rr >= c) { rr -= c; m >>= 2;  pos += 2; }
        c = (unsigned)__popcll(m & 0x1ull);
        if ((unsigned)rr >= c) { rr -= c; m >>= 1;  pos += 1; }
        lst[off + lane] = (unsigned short)((wave << 6) + pos);
    }
    __syncthreads();

    const float px  = (float)(2*ix + 1 - VWD) / 96.0f;
    const float py  = (float)(2*iy + 1 - VWD) / 96.0f;
    const float pz0 = (float)(2*(iz0+0) + 1 - VWD) / 96.0f;
    const float pz1 = (float)(2*(iz0+1) + 1 - VWD) / 96.0f;
    const float pz2 = (float)(2*(iz0+2) + 1 - VWD) / 96.0f;
    const float pz3 = (float)(2*(iz0+3) + 1 - VWD) / 96.0f;
    const float* bb = body + (size_t)b * NFAC * RECF;

    {
        unsigned fnd = 0u, pub = 0u, flv = 0u;
        // total > 32 => wave, wave+8, wave+16 all valid initially.
        int it = wave + 8;          // index of the test AFTER the current one
        int ip = wave + 16;         // record-prefetch index (lst value held)
        int f0 = __builtin_amdgcn_readfirstlane((int)lst[wave]);
        int f1 = __builtin_amdgcn_readfirstlane((int)lst[it]);
        unsigned lv = lst[ip];      // lst value one step ahead
        Rec r0, r1, r2;
        load_rec(r0, bb + (size_t)f0 * RECF);
        load_rec(r1, bb + (size_t)f1 * RECF);

#define HSTEP(RC, RP)                                                   \
        {                                                               \
            unsigned fln = fl[lane];            /* issue early */       \
            int ipn = ip + 8;                                           \
            unsigned lvn = lst[ipn < total ? ipn : wave];               \
            int fp = __builtin_amdgcn_readfirstlane((int)lv);           \
            load_rec(RP, bb + (size_t)fp * RECF);                       \
            facet_test_reg(RC, px, py, pz0, pz1, pz2, pz3, fnd);        \
            fnd |= flv;                         /* stale union */       \
            if (fnd != pub) { atomicOr(&fl[lane], fnd); pub = fnd; }    \
            if (__all(fnd == 15u) || it >= total) goto hend;            \
            flv = fln; lv = lvn; it += 8; ip = ipn;                     \
        }
        for (;;) { HSTEP(r0, r2) HSTEP(r1, r0) HSTEP(r2, r1) }
#undef HSTEP
hend:
        if (fnd != pub) atomicOr(&fl[lane], fnd);
    }
    __syncthreads();
    if (threadIdx.x < 64) {
        unsigned u = fl[threadIdx.x];
        float4 v;
        v.x = (u & 1u) ? 1.0f : 0.0f;
        v.y = (u & 2u) ? 1.0f : 0.0f;
        v.z = (u & 4u) ? 1.0f : 0.0f;
        v.w = (u & 8u) ? 1.0f : 0.0f;
        *(float4*)&out[(size_t)b*(VWD*VWD*VWD) + (size_t)ix*(VWD*VWD) + iy*VWD + iz0] = v;
    }
}

extern "C" void kernel_launch(void* const* d_in, const int* in_sizes, int n_in,
                              void* d_out, int out_size, void* d_ws, size_t ws_size,
                              hipStream_t stream) {
    const float* vertices = (const float*)d_in[0];   // (8, 2048, 3) f32
    const int*   facets   = (const int*)d_in[1];     // (8, 512, 4) int
    float*       out      = (float*)d_out;           // (8, 96, 96, 96) f32

    // d_ws layout:
    //   cul SoA     26*8*512*4 = 425984   @ 0
    //   body        8*512*16*4 = 262144   @ 425984
    //   masks       8*3456*8*8 = 1769472  @ 688128
    //   fullmask    8*144*4    = 4608     @ 2457600   (end ~2.46 MB)
    float* cul  = (float*)d_ws;
    float* body = (float*)((char*)d_ws + 425984);
    unsigned long long* msk = (unsigned long long*)((char*)d_ws + 688128);
    unsigned* fullmask = (unsigned*)((char*)d_ws + 2457600);

    precompute_kernel<<<NBATCH, 512, 0, stream>>>(vertices, facets, cul, body);
    mask_kernel<<<dim3(144, NBATCH), 512, 0, stream>>>(cul, msk, fullmask);
    voxelize_heavy<<<dim3(NSLAB, NBATCH), 512, 0, stream>>>(body, msk, fullmask, out);
    voxelize_light<<<dim3(NSLAB/2, NBATCH), 128, 0, stream>>>(body, msk, fullmask, out);
}

// Round 6
// 175.579 us; speedup vs baseline: 1.0897x; 1.0897x over previous
//
#include <hip/hip_runtime.h>

// Match numpy f32 semantics: no FMA contraction anywhere in this TU.
#pragma clang fp contract(off)

#define VWD 96
#define NVERT 2048
#define NFAC 512
#define NBATCH 8
#define RECF 16             // floats per facet body record
#define CULC 26             // cull components (SoA): bbox 6 + 4 planes x 4 + 4 containment deltas
#define TLIGHT 32           // candidate-count threshold: <=T wave-serial, >T 8-wave coop

// SoA cull addressing: component c, batch b, facet f
#define CUL(c, b, f) cul[(size_t)(c) * (NBATCH * NFAC) + (size_t)(b) * NFAC + (f)]

// ---------------------------------------------------------------------------
// Kernel 1: per-batch facet precompute, ordered by |det| descending via a
// ONE-BARRIER rank sort. Body records SIGN-FOLDED: det<0 => negate A,det
// (IEEE negation commutes exactly through mul/add/div).
//   body[b][s][16] : det,v3x,v3y,v3z, A00..A22, dhi, mhi, pad
//   dhi/mhi: definite/maybe-inside bounds on the numerator sum (+-1e-25
//   guards det=0 degenerate facets: ref l=NaN=outside).
// Per-plane containment delta D_i = -(M + 2E + 2e-3): slab center passing
// d_i <= D_i for all 4 planes => whole slab definitely inside (convexity;
// plane row and adjugate row are both 2*face-area so |det| cancels; margin
// ~1.8e-3 in barycentric units >> ref rounding shell; degenerate facets
// cannot pass).
// ---------------------------------------------------------------------------
__global__ __launch_bounds__(512) void precompute_kernel(
    const float* __restrict__ vertices,
    const int*   __restrict__ facets,
    float*       __restrict__ cul,
    float*       __restrict__ body)
{
    __shared__ unsigned skey[NFAC];
    const int b = blockIdx.x;
    const int j = threadIdx.x;          // one facet per thread
    const float* vb = vertices + (size_t)b * NVERT * 3;

    int4 fi = ((const int4*)facets)[b * NFAC + j];
    float x0 = vb[3*fi.x+0], y0 = vb[3*fi.x+1], z0 = vb[3*fi.x+2];
    float x1 = vb[3*fi.y+0], y1 = vb[3*fi.y+1], z1 = vb[3*fi.y+2];
    float x2 = vb[3*fi.z+0], y2 = vb[3*fi.z+1], z2 = vb[3*fi.z+2];
    float x3 = vb[3*fi.w+0], y3 = vb[3*fi.w+1], z3 = vb[3*fi.w+2];
    float a  = x0-x3, bb = x1-x3, c  = x2-x3;
    float d  = y0-y3, e  = y1-y3, f  = y2-y3;
    float g  = z0-z3, h  = z1-z3, ii = z2-z3;
    float A00 = e*ii - f*h,  A01 = c*h  - bb*ii, A02 = bb*f - c*e;
    float A10 = f*g  - d*ii, A11 = a*ii - c*g,   A12 = c*d  - a*f;
    float A20 = d*h  - e*g,  A21 = bb*g - a*h,   A22 = a*e  - bb*d;
    float det = a*(e*ii - f*h) - bb*(d*ii - f*g) + c*(d*h - e*g);
    if (det < 0.0f) {   // sign-fold (exact)
        det = -det;
        A00 = -A00; A01 = -A01; A02 = -A02;
        A10 = -A10; A11 = -A11; A12 = -A12;
        A20 = -A20; A21 = -A21; A22 = -A22;
    }
    unsigned myk = ~__float_as_uint(det);   // ascending key == descending |det|
    skey[j] = myk;
    __syncthreads();

    // rank = #{k : key_k < myk or (key_k == myk and k < j)}  -> unique slot
    int rank = 0;
    const uint4* sk4 = (const uint4*)skey;
    for (int k0 = 0; k0 < NFAC; k0 += 4) {
        uint4 kk = sk4[k0 >> 2];
        rank += (kk.x < myk) + ((kk.x == myk) & (k0 + 0 < j));
        rank += (kk.y < myk) + ((kk.y == myk) & (k0 + 1 < j));
        rank += (kk.z < myk) + ((kk.z == myk) & (k0 + 2 < j));
        rank += (kk.w < myk) + ((kk.w == myk) & (k0 + 3 < j));
    }

    CUL(0, b, rank) = fminf(fminf(x0,x1),fminf(x2,x3)) - 1e-4f;
    CUL(1, b, rank) = fminf(fminf(y0,y1),fminf(y2,y3)) - 1e-4f;
    CUL(2, b, rank) = fminf(fminf(z0,z1),fminf(z2,z3)) - 1e-4f;
    CUL(3, b, rank) = fmaxf(fmaxf(x0,x1),fmaxf(x2,x3)) + 1e-4f;
    CUL(4, b, rank) = fmaxf(fmaxf(y0,y1),fmaxf(y2,y3)) + 1e-4f;
    CUL(5, b, rank) = fmaxf(fmaxf(z0,z1),fmaxf(z2,z3)) + 1e-4f;

    // 4 outward face planes, margin-inflated, slab half-extents folded:
    // overlap test:      dot(n, slab_center) - rhs <= 0   (conservative)
    // containment test:  dot(n, slab_center) - rhs <= D   (definite)
    const float HX = 7.0f/96.0f, HZ = 3.0f/96.0f;
    auto plane = [&](float pax, float pay, float paz,
                     float pbx, float pby, float pbz,
                     float pcx, float pcy, float pcz,
                     float pox, float poy, float poz, int base, int pi) {
        float e1x = pbx-pax, e1y = pby-pay, e1z = pbz-paz;
        float e2x = pcx-pax, e2y = pcy-pay, e2z = pcz-paz;
        float nx = e1y*e2z - e1z*e2y;
        float ny = e1z*e2x - e1x*e2z;
        float nz = e1x*e2y - e1y*e2x;
        float sdot = nx*(pox-pax) + ny*(poy-pay) + nz*(poz-paz);
        if (sdot > 0.0f) { nx=-nx; ny=-ny; nz=-nz; sdot=-sdot; }
        float dpl = nx*pax + ny*pay + nz*paz;
        float n1s = fabsf(nx)+fabsf(ny)+fabsf(nz);
        float M = 1e-4f*(-sdot) + 1e-4f*n1s + 1e-4f;
        float E = fabsf(nx)*HX + fabsf(ny)*HX + fabsf(nz)*HZ;
        float rhs = dpl + M + E;
        CUL(base+0, b, rank) = nx;
        CUL(base+1, b, rank) = ny;
        CUL(base+2, b, rank) = nz;
        CUL(base+3, b, rank) = rhs;
        CUL(22+pi, b, rank) = -(M + 2.0f*E + 2e-3f);   // containment delta
    };
    plane(x1,y1,z1, x2,y2,z2, x3,y3,z3, x0,y0,z0, 6, 0);    // opposite v0
    plane(x0,y0,z0, x2,y2,z2, x3,y3,z3, x1,y1,z1, 10, 1);   // opposite v1
    plane(x0,y0,z0, x1,y1,z1, x3,y3,z3, x2,y2,z2, 14, 2);   // opposite v2
    plane(x0,y0,z0, x1,y1,z1, x2,y2,z2, x3,y3,z3, 18, 3);   // opposite v3

    float* bo = body + ((size_t)b * NFAC + rank) * RECF;
    bo[0]  = det; bo[1]  = x3;  bo[2]  = y3;  bo[3]  = z3;
    bo[4]  = A00; bo[5]  = A01; bo[6]  = A02; bo[7]  = A10;
    bo[8]  = A11; bo[9]  = A12; bo[10] = A20; bo[11] = A21;
    bo[12] = A22;
    bo[13] = det * (1.0f - 1e-5f) - 1e-25f;   // dhi
    bo[14] = det * (1.0f + 1e-5f) + 1e-25f;   // mhi
    bo[15] = 0.0f;
}

// Facet body record in wave-uniform registers (s_load via readfirstlane'd idx).
struct Rec {
    float det, v3x, v3y, v3z;
    float A00, A01, A02, A10, A11, A12, A20, A21, A22;
    float dhi, mhi;
};

__device__ __forceinline__ void load_rec(Rec& r, const float* __restrict__ bo)
{
    float4 q0 = *(const float4*)(bo + 0);
    float4 q1 = *(const float4*)(bo + 4);
    float4 q2 = *(const float4*)(bo + 8);
    float4 q3 = *(const float4*)(bo + 12);
    r.det = q0.x; r.v3x = q0.y; r.v3y = q0.z; r.v3z = q0.w;
    r.A00 = q1.x; r.A01 = q1.y; r.A02 = q1.z; r.A10 = q1.w;
    r.A11 = q2.x; r.A12 = q2.y; r.A20 = q2.z; r.A21 = q2.w;
    r.A22 = q3.x; r.dhi = q3.y; r.mhi = q3.z;
}

// Scalarize a wave-uniform 64-bit value (LDS reads land in VGPRs otherwise;
// R5 lesson: dropping readfirstlane ballooned VGPR 20->52 and turned record
// s_loads into per-lane vector loads).
__device__ __forceinline__ unsigned long long rfl64(unsigned long long v)
{
    unsigned lo = __builtin_amdgcn_readfirstlane((unsigned)v);
    unsigned hi = __builtin_amdgcn_readfirstlane((unsigned)(v >> 32));
    return ((unsigned long long)hi << 32) | lo;
}

// Position of the (r+1)-th set bit of m (r 0-based, r < popcll(m)).
__device__ __forceinline__ int nth_set_bit(unsigned long long m, int r)
{
    int pos = 0;
    unsigned c;
    c = (unsigned)__popcll(m & 0xFFFFFFFFull);
    if ((unsigned)r >= c) { r -= c; m >>= 32; pos += 32; }
    c = (unsigned)__popcll(m & 0xFFFFull);
    if ((unsigned)r >= c) { r -= c; m >>= 16; pos += 16; }
    c = (unsigned)__popcll(m & 0xFFull);
    if ((unsigned)r >= c) { r -= c; m >>= 8;  pos += 8; }
    c = (unsigned)__popcll(m & 0xFull);
    if ((unsigned)r >= c) { r -= c; m >>= 4;  pos += 4; }
    c = (unsigned)__popcll(m & 0x3ull);
    if ((unsigned)r >= c) { r -= c; m >>= 2;  pos += 2; }
    c = (unsigned)__popcll(m & 0x1ull);
    if ((unsigned)r >= c) { r -= c; m >>= 1;  pos += 1; }
    return pos;
}

// ---------------------------------------------------------------------------
// Per-candidate exact test on a register-resident record. Numerators
// bit-identical to ref; exact l_i>=0 sign test; det-relative shell on the
// sum; ONE __any branch per candidate guards the (rare) exact-division path.
// ---------------------------------------------------------------------------
__device__ __forceinline__ void facet_test_reg(
    const Rec& rr,
    float px, float py, float pz0, float pz1, float pz2, float pz3,
    unsigned& fnd)
{
    float dx = px - rr.v3x, dy = py - rr.v3y;
    // ref-exact partials (left-assoc, contract off)
    float p0 = rr.A00*dx + rr.A01*dy;
    float p1 = rr.A10*dx + rr.A11*dy;
    float p2 = rr.A20*dx + rr.A21*dy;
    float dzk0 = pz0 - rr.v3z, dzk1 = pz1 - rr.v3z;
    float dzk2 = pz2 - rr.v3z, dzk3 = pz3 - rr.v3z;
    unsigned need = 0u;   // bit k: lane in shell, must run exact path
#pragma unroll
    for (int k = 0; k < 4; ++k) {
        float dzk = (k == 0) ? dzk0 : (k == 1) ? dzk1
                  : (k == 2) ? dzk2 : dzk3;
        float n0 = p0 + rr.A02*dzk;
        float n1 = p1 + rr.A12*dzk;
        float n2 = p2 + rr.A22*dzk;
        float sm = (n0 + n1) + n2;
        float mn = fminf(fminf(n0, n1), n2);   // v_min3_f32
        bool ge0 = (mn >= 0.0f);               // EXACT l_i>=0 test
        bool def = ge0 & (sm <= rr.dhi);
        bool may = ge0 & (sm <= rr.mhi);
        if (may & !def & !((fnd >> k) & 1u)) need |= (1u << k);
        if (def) fnd |= (1u << k);
    }
    if (__any(need != 0u)) {
#pragma unroll
        for (int k = 0; k < 4; ++k) {
            float dzk = (k == 0) ? dzk0 : (k == 1) ? dzk1
                      : (k == 2) ? dzk2 : dzk3;
            float n0 = p0 + rr.A02*dzk;
            float n1 = p1 + rr.A12*dzk;
            float n2 = p2 + rr.A22*dzk;
            float l0 = n0 / rr.det;
            float l1 = n1 / rr.det;
            float l2 = n2 / rr.det;
            float l3 = 1.0f - ((l0 + l1) + l2);
            bool inside = (l0 >= 0.0f) & (l0 <= 1.0f) &
                          (l1 >= 0.0f) & (l1 <= 1.0f) &
                          (l2 >= 0.0f) & (l2 <= 1.0f) &
                          (l3 >= 0.0f) & (l3 <= 1.0f);
            if (((need >> k) & 1u) & inside) fnd |= (1u << k);
        }
    }
}

// ---------------------------------------------------------------------------
// Kernel 2 (FUSED mask + voxelize, R6): one 512-thread block per
// (batch, column, z-octet). Grid 144*3 x 8 = 3456 blocks (was 4 dispatches /
// 40k+ blocks across mask+heavy+light).
// Phase A (ex-mask_kernel): facet-per-lane, cull record loaded once; wave w's
//   __ballot over its 64 facets IS mask word w, for each of the block's 8
//   slabs (fresh plane-dot at the octet base + 7 increments — error budget
//   identical to the old 23-increment version, margins unchanged). Words +
//   per-wave containment bits exchanged through 576 B of LDS; ONE barrier.
// Phase B: wave w owns slab w. Fully-contained -> write ones. total==0 ->
//   write zeros. total<=TLIGHT -> serial SALU cursor over the 8 words
//   (SGPR via rfl64), records via readfirstlane'd s_load, depth-1 prefetch.
// Phase C (heavy, total>TLIGHT — rare): after one barrier, all 8 waves
//   cooperate per heavy slab: LDS candidate list (wave w extracts word w,
//   offsets from local popcounts, no extra barrier), stride-8 scan with
//   stale-OK LDS per-lane union for cross-wave early exit.
// ---------------------------------------------------------------------------
__global__ __launch_bounds__(512) void voxelize_fused(
    const float* __restrict__ cul,
    const float* __restrict__ body,
    float*       __restrict__ out)
{
    __shared__ unsigned long long wsh[8][8];   // [slab-in-block][word]
    __shared__ unsigned fullw8[8];
    __shared__ unsigned totsh[8];
    __shared__ unsigned short lst[NFAC];
    __shared__ unsigned fl[64];

    const int b    = blockIdx.y;
    const int col  = blockIdx.x / 3;          // 0..143 = sx*12+sy
    const int g    = blockIdx.x % 3;          // z-octet
    const int sz0  = g * 8;
    const int wave = threadIdx.x >> 6;        // 0..7 = mask word = own slab
    const int lane = threadIdx.x & 63;
    const int f    = threadIdx.x;             // facet rank (sorted)

    // ---------------- Phase A: in-block mask build ----------------
    float bminx=CUL(0,b,f), bminy=CUL(1,b,f), bminz=CUL(2,b,f);
    float bmaxx=CUL(3,b,f), bmaxy=CUL(4,b,f), bmaxz=CUL(5,b,f);
    float n0x=CUL(6,b,f),  n0y=CUL(7,b,f),  n0z=CUL(8,b,f),  r0=CUL(9,b,f);
    float n1x=CUL(10,b,f), n1y=CUL(11,b,f), n1z=CUL(12,b,f), r1=CUL(13,b,f);
    float n2x=CUL(14,b,f), n2y=CUL(15,b,f), n2z=CUL(16,b,f), r2=CUL(17,b,f);
    float n3x=CUL(18,b,f), n3y=CUL(19,b,f), n3z=CUL(20,b,f), r3=CUL(21,b,f);
    float D0=CUL(22,b,f), D1=CUL(23,b,f), D2=CUL(24,b,f), D3=CUL(25,b,f);

    const int sx = col / 12, sy = col % 12;
    const float cx = (float)(16*sx + 8 - VWD) / 96.0f;
    const float cy = (float)(16*sy + 8 - VWD) / 96.0f;
    const float colminx = (float)(16*sx + 1  - VWD) / 96.0f;
    const float colmaxx = (float)(16*sx + 15 - VWD) / 96.0f;
    const float colminy = (float)(16*sy + 1  - VWD) / 96.0f;
    const float colmaxy = (float)(16*sy + 15 - VWD) / 96.0f;
    const bool ovxy = (bminx <= colmaxx) & (bmaxx >= colminx) &
                      (bminy <= colmaxy) & (bmaxy >= colminy);

    const float stepc = 8.0f / 96.0f;
    const float cz = (float)(8*sz0 + 4 - VWD) / 96.0f;   // center of slab sz0
    float d0 = n0x*cx + n0y*cy + n0z*cz - r0;  float t0 = n0z*stepc;
    float d1 = n1x*cx + n1y*cy + n1z*cz - r1;  float t1 = n1z*stepc;
    float d2 = n2x*cx + n2y*cy + n2z*cz - r2;  float t2 = n2z*stepc;
    float d3 = n3x*cx + n3y*cy + n3z*cz - r3;  float t3 = n3z*stepc;
    float zlo = (float)(8*sz0 + 1 - VWD) / 96.0f;
    float zhi = (float)(8*sz0 + 7 - VWD) / 96.0f;

    unsigned fullw = 0u;
#pragma unroll
    for (int s = 0; s < 8; ++s) {
        bool ov = ovxy & (bminz <= zhi) & (bmaxz >= zlo) &
                  (d0 <= 0.0f) & (d1 <= 0.0f) & (d2 <= 0.0f) & (d3 <= 0.0f);
        bool fullv = (d0 <= D0) & (d1 <= D1) & (d2 <= D2) & (d3 <= D3);
        unsigned long long bal = __ballot((int)ov);
        if (lane == 0) wsh[s][wave] = bal;
        if (__ballot((int)fullv) != 0ull) fullw |= (1u << s);
        d0 += t0; d1 += t1; d2 += t2; d3 += t3;
        zlo += stepc; zhi += stepc;
    }
    if (lane == 0) fullw8[wave] = fullw;   // own slot, unconditional: no init race
    __syncthreads();                                              // B1

    // ---------------- Phase B: own slab (light / trivial) ----------------
    const int slab_sz = sz0 + wave;
    const int ix = sx*8 + (lane >> 3);
    const int iy = sy*8 + (lane & 7);
    float* op = &out[(size_t)b*(VWD*VWD*VWD) + (size_t)ix*(VWD*VWD)
                     + iy*VWD + slab_sz*4];

    const unsigned fullbits = fullw8[0] | fullw8[1] | fullw8[2] | fullw8[3] |
                              fullw8[4] | fullw8[5] | fullw8[6] | fullw8[7];
    unsigned long long W[8];
#pragma unroll
    for (int j = 0; j < 8; ++j) W[j] = rfl64(wsh[wave][j]);
    int total = __popcll(W[0]) + __popcll(W[1]) + __popcll(W[2]) +
                __popcll(W[3]) + __popcll(W[4]) + __popcll(W[5]) +
                __popcll(W[6]) + __popcll(W[7]);
    const bool isfull = (fullbits >> wave) & 1u;
    if (isfull) total = 0;     // ones-write; convexity => all inside
    if (lane == 0) totsh[wave] = (total > TLIGHT) ? (unsigned)total : 0u;

    const float* bb = body + (size_t)b * NFAC * RECF;
    const float px  = (float)(2*ix + 1 - VWD) / 96.0f;
    const float py  = (float)(2*iy + 1 - VWD) / 96.0f;
    const float pz0 = (float)(8*slab_sz + 1 - VWD) / 96.0f;
    const float pz1 = (float)(8*slab_sz + 3 - VWD) / 96.0f;
    const float pz2 = (float)(8*slab_sz + 5 - VWD) / 96.0f;
    const float pz3 = (float)(8*slab_sz + 7 - VWD) / 96.0f;

    if (isfull) {
        float4 v; v.x = 1.0f; v.y = 1.0f; v.z = 1.0f; v.w = 1.0f;
        *(float4*)op = v;
    } else if (total == 0) {
        float4 v; v.x = 0.0f; v.y = 0.0f; v.z = 0.0f; v.w = 0.0f;
        *(float4*)op = v;
    } else if (total <= TLIGHT) {
        unsigned fnd = 0u;
        unsigned long long cm = W[0]; int cwi = 0;
#define ADV(dst)                                                        \
        {                                                               \
            while (cm == 0ull && cwi < 7) { ++cwi; cm = W[cwi]; }       \
            if (cm == 0ull) dst = -1;                                   \
            else { int bit_ = (int)__builtin_ctzll(cm);                 \
                   cm &= cm - 1ull; dst = (cwi << 6) + bit_; }          \
        }
        int fcur; ADV(fcur);               // total > 0 => valid
        Rec rc;
        load_rec(rc, bb + (size_t)__builtin_amdgcn_readfirstlane(fcur) * RECF);
        for (;;) {
            int fnx; ADV(fnx);
            int fpre = __builtin_amdgcn_readfirstlane(fnx >= 0 ? fnx : fcur);
            Rec rn; load_rec(rn, bb + (size_t)fpre * RECF);  // depth-1 prefetch
            facet_test_reg(rc, px, py, pz0, pz1, pz2, pz3, fnd);
            if (__all(fnd == 15u) || fnx < 0) break;
            fcur = fnx; rc = rn;
        }
#undef ADV
        float4 v;
        v.x = (fnd & 1u) ? 1.0f : 0.0f;
        v.y = (fnd & 2u) ? 1.0f : 0.0f;
        v.z = (fnd & 4u) ? 1.0f : 0.0f;
        v.w = (fnd & 8u) ? 1.0f : 0.0f;
        *(float4*)op = v;
    }
    __syncthreads();                                              // B2

    // ---------------- Phase C: heavy slabs (cooperative) ----------------
    unsigned hv = 0u;
#pragma unroll
    for (int s = 0; s < 8; ++s) if (totsh[s] != 0u) hv |= (1u << s);
    if (hv == 0u) return;                       // block-uniform

    for (int h = 0; h < 8; ++h) {
        if (!((hv >> h) & 1u)) continue;        // uniform
        const int total_h = (int)totsh[h];
        if (threadIdx.x < 64) fl[threadIdx.x] = 0u;
        // list build: wave w extracts word w of slab h (offsets local)
        unsigned long long mh = rfl64(wsh[h][wave]);
        int off = 0;
        for (int j = 0; j < 8; ++j) {
            if (j < wave) off += __popcll(rfl64(wsh[h][j]));
        }
        const int ch = __popcll(mh);
        if (lane < ch)
            lst[off + lane] = (unsigned short)((wave << 6) + nth_set_bit(mh, lane));
        __syncthreads();                                          // B3

        {
            const int hsz = sz0 + h;
            const float hz0 = (float)(8*hsz + 1 - VWD) / 96.0f;
            const float hz1 = (float)(8*hsz + 3 - VWD) / 96.0f;
            const float hz2 = (float)(8*hsz + 5 - VWD) / 96.0f;
            const float hz3 = (float)(8*hsz + 7 - VWD) / 96.0f;
            unsigned fnd = 0u, pub = 0u;
            int i = wave;                       // total_h > TLIGHT >= 8
            int fc = __builtin_amdgcn_readfirstlane((int)lst[i]);
            Rec rc; load_rec(rc, bb + (size_t)fc * RECF);
            for (;;) {
                int inext = i + 8;
                int fn = __builtin_amdgcn_readfirstlane(
                             (int)lst[inext < total_h ? inext : i]);
                Rec rn; load_rec(rn, bb + (size_t)fn * RECF);
                unsigned flv = fl[lane];        // stale union (monotonic OR)
                facet_test_reg(rc, px, py, hz0, hz1, hz2, hz3, fnd);
                fnd |= flv;
                if (fnd != pub) { atomicOr(&fl[lane], fnd); pub = fnd; }
                if (__all(fnd == 15u) || inext >= total_h) break;
                i = inext; rc = rn;
            }
            if (fnd != pub) atomicOr(&fl[lane], fnd);
        }
        __syncthreads();                                          // B4
        if (threadIdx.x < 64) {
            unsigned u = fl[threadIdx.x];
            const int hix = sx*8 + (threadIdx.x >> 3);
            const int hiy = sy*8 + (threadIdx.x & 7);
            float4 v;
            v.x = (u & 1u) ? 1.0f : 0.0f;
            v.y = (u & 2u) ? 1.0f : 0.0f;
            v.z = (u & 4u) ? 1.0f : 0.0f;
            v.w = (u & 8u) ? 1.0f : 0.0f;
            *(float4*)&out[(size_t)b*(VWD*VWD*VWD) + (size_t)hix*(VWD*VWD)
                           + hiy*VWD + (sz0 + h)*4] = v;
        }
        // fl reset at next iteration happens in threads<64 AFTER their own
        // fl read+write here (program order); no other thread touches fl
        // between B4 and the next B3.
    }
}

extern "C" void kernel_launch(void* const* d_in, const int* in_sizes, int n_in,
                              void* d_out, int out_size, void* d_ws, size_t ws_size,
                              hipStream_t stream) {
    const float* vertices = (const float*)d_in[0];   // (8, 2048, 3) f32
    const int*   facets   = (const int*)d_in[1];     // (8, 512, 4) int
    float*       out      = (float*)d_out;           // (8, 96, 96, 96) f32

    // d_ws layout:
    //   cul SoA     26*8*512*4 = 425984   @ 0
    //   body        8*512*16*4 = 262144   @ 425984   (end ~688 KB)
    float* cul  = (float*)d_ws;
    float* body = (float*)((char*)d_ws + 425984);

    precompute_kernel<<<NBATCH, 512, 0, stream>>>(vertices, facets, cul, body);
    voxelize_fused<<<dim3(144 * 3, NBATCH), 512, 0, stream>>>(cul, body, out);
}